// Round 7
// baseline (822.114 us; speedup 1.0000x reference)
//
#include <hip/hip_runtime.h>

// Problem constants
#define NN      81920
#define BB      4096
#define PP      20
#define DD      128
#define DOUTT   256
#define MAXDEGG 8
#define NBLK_B  160   // bucketing blocks (160 x 512 = 81920)

using bf16x8 = __attribute__((ext_vector_type(8))) short;
using f32x4  = __attribute__((ext_vector_type(4))) float;
using u16x4  = __attribute__((ext_vector_type(4))) ushort;

__device__ __forceinline__ float b2f(ushort u) {
    union { unsigned u; float f; } v; v.u = ((unsigned)u) << 16; return v.f;
}
__device__ __forceinline__ ushort f2b(float f) {
    union { float f; unsigned u; } v; v.f = f;
    unsigned r = v.u + 0x7fffu + ((v.u >> 16) & 1u);
    return (ushort)(r >> 16);
}
__device__ __forceinline__ float sigm(float x) {
    return __fdividef(1.f, 1.f + __expf(-x));
}
__device__ __forceinline__ float tanh_fast(float x) {
    return 1.f - __fdividef(2.f, 1.f + __expf(2.f * x));
}
__device__ __forceinline__ f32x4 mfma16(bf16x8 a, bf16x8 b, f32x4 c) {
    return __builtin_amdgcn_mfma_f32_16x16x32_bf16(a, b, c, 0, 0, 0);
}
__device__ __forceinline__ bf16x8 pack8(float4 a, float4 b) {
    bf16x8 r;
    r[0] = (short)f2b(a.x); r[1] = (short)f2b(a.y);
    r[2] = (short)f2b(a.z); r[3] = (short)f2b(a.w);
    r[4] = (short)f2b(b.x); r[5] = (short)f2b(b.y);
    r[6] = (short)f2b(b.z); r[7] = (short)f2b(b.w);
    return r;
}
__device__ __forceinline__ bf16x8 ld8_bf(const ushort* p) { return *(const bf16x8*)p; }
__device__ __forceinline__ bf16x8 ld8_f32(const float* p) {
    return pack8(*(const float4*)p, *(const float4*)(p + 4));
}

// ---------------- degree bucketing: atomic-free, stable, deterministic -----
__global__ __launch_bounds__(512) void hist_k(const int* __restrict__ deg,
                                              int* __restrict__ blockHist) {
    __shared__ int wh[8][9];
    const int t = threadIdx.x, w = t >> 6, lane = t & 63;
    int d = deg[blockIdx.x * 512 + t]; d = min(max(d, 0), 8);
#pragma unroll
    for (int c = 0; c < 9; ++c) {
        unsigned long long m = __ballot(d == c);
        if (lane == 0) wh[w][c] = __popcll(m);
    }
    __syncthreads();
    if (t < 9) {
        int s = 0;
#pragma unroll
        for (int w2 = 0; w2 < 8; ++w2) s += wh[w2][t];
        blockHist[blockIdx.x * 9 + t] = s;
    }
}
__global__ void scan_k(const int* __restrict__ blockHist,
                       int* __restrict__ blockBase) {
    __shared__ int classTot[9], classStart[9];
    const int c = threadIdx.x;
    if (c < 9) {
        int s = 0;
        for (int b = 0; b < NBLK_B; ++b) s += blockHist[b * 9 + c];
        classTot[c] = s;
    }
    __syncthreads();
    if (c == 0) {
        int acc = 0;
        for (int k = 0; k < 9; ++k) { classStart[k] = acc; acc += classTot[k]; }
    }
    __syncthreads();
    if (c < 9) {
        int acc = classStart[c];
        for (int b = 0; b < NBLK_B; ++b) {
            blockBase[b * 9 + c] = acc;
            acc += blockHist[b * 9 + c];
        }
    }
}
__global__ __launch_bounds__(512) void scatter_k(const int* __restrict__ deg,
                                                 const int* __restrict__ blockBase,
                                                 int* __restrict__ perm) {
    __shared__ int wh[8][9];
    __shared__ int wbase[8][9];
    const int t = threadIdx.x, w = t >> 6, lane = t & 63;
    const int i = blockIdx.x * 512 + t;
    int d = deg[i]; d = min(max(d, 0), 8);
    int lt = 0;
#pragma unroll
    for (int c = 0; c < 9; ++c) {
        unsigned long long m = __ballot(d == c);
        if (lane == 0) wh[w][c] = __popcll(m);
        if (d == c) lt = __popcll(m & ((1ull << lane) - 1ull));
    }
    __syncthreads();
    if (t < 72) {
        const int w2 = t / 9, c = t - w2 * 9;
        int s = blockBase[blockIdx.x * 9 + c];
        for (int k = 0; k < w2; ++k) s += wh[k][c];
        wbase[w2][c] = s;
    }
    __syncthreads();
    perm[wbase[w][d] + lt] = i;
}

// ---------------- BN stats over feat (f32) ----------------
__global__ __launch_bounds__(256) void bn_stats(const float* __restrict__ X,
                                                float* __restrict__ part) {
    const int tid  = threadIdx.x;
    const int col  = tid & 127;
    const int half = tid >> 7;
    const long base = (long)blockIdx.x * 128 + (long)half * 64;
    float s = 0.f, q = 0.f;
    for (int i = 0; i < 64; ++i) {
        float x = X[(base + i) * 128 + col];
        s += x; q += x * x;
    }
    __shared__ float red[2][2][128];
    red[0][half][col] = s;
    red[1][half][col] = q;
    __syncthreads();
    if (tid < 128) {
        part[blockIdx.x * 128 + tid]             = red[0][0][tid] + red[0][1][tid];
        part[640 * 128 + blockIdx.x * 128 + tid] = red[1][0][tid] + red[1][1][tid];
    }
}

// 1 block x 128 threads; nparts-parameterized
__global__ void bn_final(const float* __restrict__ part, int nparts,
                         const float* __restrict__ g, const float* __restrict__ b,
                         float2* __restrict__ ss) {
    const int c = threadIdx.x;
    float s = 0.f, q = 0.f;
    for (int i = 0; i < nparts; ++i) {
        s += part[i * 128 + c];
        q += part[nparts * 128 + i * 128 + c];
    }
    const float inv_n = 1.f / (float)NN;
    float mean = s * inv_n;
    float var  = q * inv_n - mean * mean;
    float rstd = rsqrtf(var + 1e-5f);
    float sc = g[c] * rstd;
    ss[c] = make_float2(sc, b[c] - mean * sc);
}

// ---------------- Generic fused GEMM --------------------------------------
// out[m,c] = sum_k A1[m,k]W1'[c,k] + (KPARTS==2) A2[m2,k]W2'[c,k] + biases
// FOLDx: W' = sc*W folded at load; fold-bias = sum_k sh[k]W[c,k] via shfl.
// OUTMODE: 0=bf16 out, 1=f32 out, 2=bf16 out + BN-stats partials,
//          3=e-epilogue only (e[row] = sum_c sigm(v+fvl[b,c])*We[c])
template <int NCOL, int KPARTS, bool A1F32, bool GATHER2, bool BIAS1, bool BIAS2,
          bool FOLD1, bool FOLD2, int OUTMODE>
__global__ __launch_bounds__(256) void gemm_bt(
    const void* __restrict__ A1, const void* __restrict__ A2,
    const float* __restrict__ W1, const float* __restrict__ W2,
    const float* __restrict__ bias1, const float* __restrict__ bias2,
    const float2* __restrict__ ssW1, const float2* __restrict__ ssW2,
    const int* __restrict__ gidx, void* __restrict__ outv,
    float* __restrict__ part, int nparts,
    const float* __restrict__ fvl, const float* __restrict__ We,
    float* __restrict__ e) {
    constexpr int JT = NCOL / 64;
    __shared__ float epart[4][64];
    const int tid = threadIdx.x;
    const int w   = tid >> 6;
    const int l   = tid & 63;
    const int l15 = l & 15;
    const int l4  = l >> 4;
    const int colbase = w * (NCOL / 4);

    bf16x8 bfr[JT][KPARTS * 4];
    float bv[JT];
    float Wec[JT];
#pragma unroll
    for (int jl = 0; jl < JT; ++jl) {
        const int wrow = colbase + jl * 16 + l15;
        float fb = 0.f;
#pragma unroll
        for (int kp = 0; kp < KPARTS; ++kp) {
            const float* Wp = (kp == 0) ? W1 : W2;
            const float2* sp = (kp == 0) ? ssW1 : ssW2;
            const bool fold = (kp == 0) ? FOLD1 : FOLD2;
#pragma unroll
            for (int kt = 0; kt < 4; ++kt) {
                const float* wp = &Wp[(long)wrow * 128 + kt * 32 + l4 * 8];
                float4 a = *(const float4*)wp;
                float4 b4 = *(const float4*)(wp + 4);
                if (fold) {
                    const float* s = (const float*)(sp + kt * 32 + l4 * 8);
                    float4 s0 = *(const float4*)s, s1 = *(const float4*)(s + 4);
                    float4 s2 = *(const float4*)(s + 8), s3 = *(const float4*)(s + 12);
                    fb += s0.y * a.x + s0.w * a.y + s1.y * a.z + s1.w * a.w
                        + s2.y * b4.x + s2.w * b4.y + s3.y * b4.z + s3.w * b4.w;
                    a.x *= s0.x; a.y *= s0.z; a.z *= s1.x; a.w *= s1.z;
                    b4.x *= s2.x; b4.y *= s2.z; b4.z *= s3.x; b4.w *= s3.z;
                }
                bfr[jl][kp * 4 + kt] = pack8(a, b4);
            }
        }
        if (FOLD1 || FOLD2) {
            fb += __shfl_xor(fb, 16, 64);
            fb += __shfl_xor(fb, 32, 64);
        }
        if (BIAS1) fb += bias1[wrow];
        if (BIAS2) fb += bias2[wrow];
        bv[jl] = fb;
        if (OUTMODE == 3) Wec[jl] = We[wrow];
    }

    const int rowblk = blockIdx.x * 64;
    const f32x4 fz = {0.f, 0.f, 0.f, 0.f};
    float ssum[JT], sq[JT];
#pragma unroll
    for (int jl = 0; jl < JT; ++jl) { ssum[jl] = 0.f; sq[jl] = 0.f; }

#pragma unroll
    for (int it = 0; it < 4; ++it) {
        const int arow1 = rowblk + it * 16 + l15;
        bf16x8 afr[KPARTS * 4];
#pragma unroll
        for (int kt = 0; kt < 4; ++kt) {
            if (A1F32)
                afr[kt] = ld8_f32(&((const float*)A1)[(long)arow1 * 128 + kt * 32 + l4 * 8]);
            else
                afr[kt] = ld8_bf(&((const ushort*)A1)[(long)arow1 * 128 + kt * 32 + l4 * 8]);
        }
        if (KPARTS == 2) {
            const long arow2 = GATHER2 ? (long)gidx[arow1] : (long)arow1;
#pragma unroll
            for (int kt = 0; kt < 4; ++kt)
                afr[4 + kt] = ld8_bf(&((const ushort*)A2)[arow2 * 128 + kt * 32 + l4 * 8]);
        }
        f32x4 acc[JT];
#pragma unroll
        for (int jl = 0; jl < JT; ++jl) {
            acc[jl] = fz;
#pragma unroll
            for (int kk = 0; kk < KPARTS * 4; ++kk)
                acc[jl] = mfma16(afr[kk], bfr[jl][kk], acc[jl]);
        }
        float ps[4] = {0.f, 0.f, 0.f, 0.f};
#pragma unroll
        for (int jl = 0; jl < JT; ++jl) {
            const int col = colbase + jl * 16 + l15;
#pragma unroll
            for (int r = 0; r < 4; ++r) {
                const long orow = rowblk + it * 16 + l4 * 4 + r;
                float v = acc[jl][r] + bv[jl];
                if (OUTMODE == 0 || OUTMODE == 2)
                    ((ushort*)outv)[orow * NCOL + col] = f2b(v);
                if (OUTMODE == 1)
                    ((float*)outv)[orow * NCOL + col] = v;
                if (OUTMODE == 2) { ssum[jl] += v; sq[jl] += v * v; }
                if (OUTMODE == 3) {
                    const int b = (int)orow / PP;
                    ps[r] += sigm(v + fvl[(long)b * 128 + col]) * Wec[jl];
                }
            }
        }
        if (OUTMODE == 3) {
#pragma unroll
            for (int r = 0; r < 4; ++r) {
#pragma unroll
                for (int off = 1; off < 16; off <<= 1)
                    ps[r] += __shfl_xor(ps[r], off, 64);
            }
            if (l15 == 0) {
#pragma unroll
                for (int r = 0; r < 4; ++r)
                    epart[w][it * 16 + l4 * 4 + r] = ps[r];
            }
        }
    }
    if (OUTMODE == 2) {
#pragma unroll
        for (int jl = 0; jl < JT; ++jl) {
            float s = ssum[jl], q = sq[jl];
            s += __shfl_xor(s, 16, 64); s += __shfl_xor(s, 32, 64);
            q += __shfl_xor(q, 16, 64); q += __shfl_xor(q, 32, 64);
            if (l4 == 0) {
                const int col = colbase + jl * 16 + l15;
                part[(long)blockIdx.x * 128 + col] = s;
                part[(long)nparts * 128 + (long)blockIdx.x * 128 + col] = q;
            }
        }
    }
    if (OUTMODE == 3) {
        __syncthreads();
        if (tid < 64)
            e[rowblk + tid] = epart[0][tid] + epart[1][tid] + epart[2][tid] + epart[3][tid];
    }
}

// ---------------- Fused ragged GRU, degree-sorted blocks -------------------
// 8 waves x 64 same-degree nodes; wave owns 16 cols. Cross-barrier prefetch
// of its{0,1} gathers (12 VGPRs); waves_per_eu(4,4) pins occupancy so the
// allocator can use up to 128 VGPRs without spilling (R6 lesson).
__global__ __attribute__((amdgpu_flat_work_group_size(512, 512), amdgpu_waves_per_eu(4, 4)))
void gru_kernel(const ushort* __restrict__ G,
                const float* __restrict__ Whh,
                const float* __restrict__ bhh,
                const int* __restrict__ nbr_idx,
                const int* __restrict__ deg,
                const int* __restrict__ perm,
                ushort* __restrict__ neigh) {
    __shared__ alignas(16) ushort hbuf[2][64][136];
    __shared__ alignas(16) int nbrs[64][8];
    __shared__ int degs[64];
    __shared__ int nid[64];

    const int tid = threadIdx.x;
    const int w   = tid >> 6;
    const int l   = tid & 63;
    const int l15 = l & 15;
    const int l4  = l >> 4;
    const int blockRow = (gridDim.x - 1 - blockIdx.x) * 64;  // high-deg first
    const int colbase = w * 16;
    const int c0 = colbase + l4 * 4;

    if (tid < 64) nid[tid] = perm[blockRow + tid];
    {
        bf16x8 z = {0, 0, 0, 0, 0, 0, 0, 0};
        bf16x8* p = (bf16x8*)&hbuf[0][0][0];
        for (int i = tid; i < 64 * 136 / 8; i += 512) p[i] = z;
    }
    __syncthreads();
    nbrs[tid >> 3][tid & 7] = nbr_idx[(long)nid[tid >> 3] * 8 + (tid & 7)];
    if (tid < 64) degs[tid] = deg[nid[tid]];

    bf16x8 bfr[3][4];
#pragma unroll
    for (int g = 0; g < 3; ++g)
#pragma unroll
        for (int kt = 0; kt < 4; ++kt)
            bfr[g][kt] = ld8_f32(&Whh[(long)(g * 128 + colbase + l15) * 128 + kt * 32 + l4 * 8]);
    f32x4 binit[3];
#pragma unroll
    for (int g = 0; g < 3; ++g)
        binit[g] = *(const f32x4*)&bhh[g * 128 + c0];
    __syncthreads();

    int dreg[4];
#pragma unroll
    for (int it = 0; it < 4; ++it) dreg[it] = degs[it * 16 + l15];
    int dmax = degs[l];
#pragma unroll
    for (int off = 32; off > 0; off >>= 1) dmax = max(dmax, __shfl_xor(dmax, off, 64));
    dmax = __builtin_amdgcn_readfirstlane(dmax);

    // cross-barrier prefetch buffer for its {0,1}
    u16x4 gP[2][3];
#pragma unroll
    for (int it = 0; it < 2; ++it) {
        gP[it][0] = (u16x4){0,0,0,0}; gP[it][1] = (u16x4){0,0,0,0}; gP[it][2] = (u16x4){0,0,0,0};
        if (0 < dreg[it]) {
            const ushort* Grow = G + (long)nbrs[it * 16 + l15][0] * 384;
            gP[it][0] = *(const u16x4*)&Grow[c0];
            gP[it][1] = *(const u16x4*)&Grow[c0 + 128];
            gP[it][2] = *(const u16x4*)&Grow[c0 + 256];
        }
    }

    int cur = 0;
    for (int t = 0; t < dmax; ++t) {
        // in-step loads for its {2,3} (compiler hoists these early)
        u16x4 g23[2][3];
#pragma unroll
        for (int it = 2; it < 4; ++it) {
            u16x4* gd = g23[it - 2];
            gd[0] = (u16x4){0,0,0,0}; gd[1] = (u16x4){0,0,0,0}; gd[2] = (u16x4){0,0,0,0};
            if (t < dreg[it]) {
                const ushort* Grow = G + (long)nbrs[it * 16 + l15][t] * 384;
                gd[0] = *(const u16x4*)&Grow[c0];
                gd[1] = *(const u16x4*)&Grow[c0 + 128];
                gd[2] = *(const u16x4*)&Grow[c0 + 256];
            }
        }

#pragma unroll
        for (int it = 0; it < 2; ++it) {
            const int row = it * 16 + l15;
            const bool upd = (t < dreg[it]);
            bf16x8 af[4];
#pragma unroll
            for (int kt = 0; kt < 4; ++kt)
                af[kt] = *(const bf16x8*)&hbuf[cur][row][kt * 32 + l4 * 8];
            f32x4 ar = binit[0], az = binit[1], an = binit[2];
#pragma unroll
            for (int kt = 0; kt < 4; ++kt) {
                ar = mfma16(bfr[0][kt], af[kt], ar);
                az = mfma16(bfr[1][kt], af[kt], az);
                an = mfma16(bfr[2][kt], af[kt], an);
            }
            const u16x4 hold = *(const u16x4*)&hbuf[cur][row][c0];
            u16x4 hnew = hold;
            if (upd) {
#pragma unroll
                for (int r = 0; r < 4; ++r) {
                    const float rr = sigm(b2f(gP[it][0][r]) + ar[r]);
                    const float zz = sigm(b2f(gP[it][1][r]) + az[r]);
                    const float nn = tanh_fast(b2f(gP[it][2][r]) + rr * an[r]);
                    hnew[r] = f2b((1.f - zz) * nn + zz * b2f(hold[r]));
                }
            }
            *(u16x4*)&hbuf[1 - cur][row][c0] = hnew;
        }

        // prefetch NEXT step's its {0,1}; latency hides under its {2,3} compute
#pragma unroll
        for (int it = 0; it < 2; ++it) {
            gP[it][0] = (u16x4){0,0,0,0}; gP[it][1] = (u16x4){0,0,0,0}; gP[it][2] = (u16x4){0,0,0,0};
            if (t + 1 < dreg[it]) {
                const ushort* Grow = G + (long)nbrs[it * 16 + l15][t + 1] * 384;
                gP[it][0] = *(const u16x4*)&Grow[c0];
                gP[it][1] = *(const u16x4*)&Grow[c0 + 128];
                gP[it][2] = *(const u16x4*)&Grow[c0 + 256];
            }
        }

#pragma unroll
        for (int it = 2; it < 4; ++it) {
            const int row = it * 16 + l15;
            const bool upd = (t < dreg[it]);
            bf16x8 af[4];
#pragma unroll
            for (int kt = 0; kt < 4; ++kt)
                af[kt] = *(const bf16x8*)&hbuf[cur][row][kt * 32 + l4 * 8];
            f32x4 ar = binit[0], az = binit[1], an = binit[2];
#pragma unroll
            for (int kt = 0; kt < 4; ++kt) {
                ar = mfma16(bfr[0][kt], af[kt], ar);
                az = mfma16(bfr[1][kt], af[kt], az);
                an = mfma16(bfr[2][kt], af[kt], an);
            }
            const u16x4 hold = *(const u16x4*)&hbuf[cur][row][c0];
            u16x4 hnew = hold;
            if (upd) {
#pragma unroll
                for (int r = 0; r < 4; ++r) {
                    const float rr = sigm(b2f(g23[it - 2][0][r]) + ar[r]);
                    const float zz = sigm(b2f(g23[it - 2][1][r]) + az[r]);
                    const float nn = tanh_fast(b2f(g23[it - 2][2][r]) + rr * an[r]);
                    hnew[r] = f2b((1.f - zz) * nn + zz * b2f(hold[r]));
                }
            }
            *(u16x4*)&hbuf[1 - cur][row][c0] = hnew;
        }
        __syncthreads();
        cur ^= 1;
    }
    for (int idx = tid; idx < 64 * 16; idx += 512) {
        const int row = idx >> 4, ch = idx & 15;
        bf16x8* dst = (bf16x8*)(neigh + (long)nid[row] * 128);
        dst[ch] = *(const bf16x8*)&hbuf[cur][row][ch * 8];
    }
}

// ---------------- fused softmax + segment sums (BN2 applied on the fly) ----
__global__ __launch_bounds__(256) void seg_k(const ushort* __restrict__ rst,
                                             const float* __restrict__ e,
                                             const float* __restrict__ pw,
                                             const float2* __restrict__ ss2,
                                             ushort* __restrict__ s12) {
    const int g = blockIdx.x * 2 + (threadIdx.x >> 7);
    const int c = threadIdx.x & 127;
    const float2 sc = ss2[c];
    float ev[PP];
    float m = -1e30f;
#pragma unroll
    for (int p = 0; p < PP; ++p) { ev[p] = e[g * PP + p]; m = fmaxf(m, ev[p]); }
    float sum = 0.f;
#pragma unroll
    for (int p = 0; p < PP; ++p) { ev[p] = __expf(ev[p] - m); sum += ev[p]; }
    const float inv = __fdividef(1.f, sum);
    float a1 = 0.f, a2 = 0.f;
#pragma unroll
    for (int p = 0; p < PP; ++p) {
        const int node = g * PP + p;
        const float hv = b2f(rst[(long)node * 128 + c]) * sc.x + sc.y;
        a1 += (ev[p] * inv) * hv;
        a2 += pw[node] * hv;
    }
    s12[(long)g * 128 + c]        = f2b(a1);
    s12[(long)(BB + g) * 128 + c] = f2b(a2);
}

// ---------------------------------------------------------------------------
extern "C" void kernel_launch(void* const* d_in, const int* in_sizes, int n_in,
                              void* d_out, int out_size, void* d_ws, size_t ws_size,
                              hipStream_t stream) {
    const float* feat    = (const float*)d_in[0];
    const float* intend  = (const float*)d_in[1];
    const float* pw      = (const float*)d_in[2];
    const int*   nbr_idx = (const int*)d_in[3];
    const int*   deg     = (const int*)d_in[4];
    const int*   last    = (const int*)d_in[5];
    const float* bn1_g   = (const float*)d_in[6];
    const float* bn1_b   = (const float*)d_in[7];
    const float* W_ih    = (const float*)d_in[8];
    const float* W_hh    = (const float*)d_in[9];
    const float* b_ih    = (const float*)d_in[10];
    const float* b_hh    = (const float*)d_in[11];
    const float* W_self  = (const float*)d_in[12];
    const float* W_neigh = (const float*)d_in[13];
    const float* bn2_g   = (const float*)d_in[14];
    const float* bn2_b   = (const float*)d_in[15];
    const float* Wu      = (const float*)d_in[16];
    const float* Wv      = (const float*)d_in[17];
    const float* bv      = (const float*)d_in[18];
    const float* Wi      = (const float*)d_in[19];
    const float* bi      = (const float*)d_in[20];
    const float* We      = (const float*)d_in[21];
    const float* Wout    = (const float*)d_in[22];
    float* out = (float*)d_out;
    char* ws = (char*)d_ws;

    // workspace layout (bytes)
    ushort* G     = (ushort*)(ws + 0L);              // 62,914,560  [N,384] bf16
    ushort* rst   = G;                               // alias (G dead after gru)
    ushort* neigh = (ushort*)(ws + 62914560L);       // 20,971,520
    float*  fvl   = (float*)(ws + 83886080L);        // 2,097,152
    float*  e     = (float*)(ws + 85983232L);        // 327,680
    ushort* s12   = (ushort*)(ws + 86310912L);       // 2,097,152
    float*  part1 = (float*)(ws + 88408064L);        // 655,360
    float*  part2 = (float*)(ws + 89063424L);        // 1,310,720
    int*    perm  = (int*)(ws + 90374144L);          // 327,680
    float2* ss1   = (float2*)(ws + 90701824L);       // 1,024
    float2* ss2   = (float2*)(ws + 90702848L);       // 1,024
    int*    blockHist = (int*)(ws + 90703872L);      // 5,760
    int*    blockBase = (int*)(ws + 90709632L);      // 5,760

    // ---- BN1 stats only (apply is folded into W of downstream GEMMs) ----
    bn_stats<<<640, 256, 0, stream>>>(feat, part1);
    bn_final<<<1, 128, 0, stream>>>(part1, 640, bn1_g, bn1_b, ss1);

    // ---- degree bucketing (atomic-free) -> perm ----
    hist_k<<<NBLK_B, 512, 0, stream>>>(deg, blockHist);
    scan_k<<<1, 16, 0, stream>>>(blockHist, blockBase);
    scatter_k<<<NBLK_B, 512, 0, stream>>>(deg, blockBase, perm);

    // ---- G = bn1(feat) @ W_ih.T + b_ih   (BN folded into W_ih) ----
    gemm_bt<384, 1, true, false, true, false, true, false, 0><<<1280, 256, 0, stream>>>(
        feat, nullptr, W_ih, nullptr, b_ih, nullptr, ss1, nullptr,
        nullptr, G, nullptr, 0, nullptr, nullptr, nullptr);

    // ---- ragged GRU (degree-sorted, high-deg first) -> neigh ----
    gru_kernel<<<1280, 512, 0, stream>>>(G, W_hh, b_hh, nbr_idx, deg, perm, neigh);

    // ---- rst = bn1(feat)@W_self.T + neigh@W_neigh.T  (+BN2-stats epilogue) ----
    gemm_bt<128, 2, true, false, false, false, true, false, 2><<<1280, 256, 0, stream>>>(
        feat, neigh, W_self, W_neigh, nullptr, nullptr, ss1, nullptr,
        nullptr, rst, part2, 1280, nullptr, nullptr, nullptr);
    bn_final<<<1, 128, 0, stream>>>(part2, 1280, bn2_g, bn2_b, ss2);

    // ---- fvl = intend@Wv.T + bv + bn2(rst)[last]@Wi.T + bi  (f32) ----
    gemm_bt<128, 2, true, true, true, true, false, true, 1><<<64, 256, 0, stream>>>(
        intend, rst, Wv, Wi, bv, bi, nullptr, ss2,
        last, fvl, nullptr, 0, nullptr, nullptr, nullptr);

    // ---- e[row] = sum_c sigm(bn2(rst)@Wu.T + fvl) * We  (fu never stored) ----
    gemm_bt<128, 1, false, false, false, false, true, false, 3><<<1280, 256, 0, stream>>>(
        rst, nullptr, Wu, nullptr, nullptr, nullptr, ss2, nullptr,
        nullptr, nullptr, nullptr, 0, fvl, We, e);

    // ---- fused softmax + segment sums -> s12 ----
    seg_k<<<2048, 256, 0, stream>>>(rst, e, pw, ss2, s12);

    // ---- [rst_g; pos] = s12 @ Wout.T -> d_out (f32) ----
    gemm_bt<256, 1, false, false, false, false, false, false, 1><<<128, 256, 0, stream>>>(
        s12, nullptr, Wout, nullptr, nullptr, nullptr, nullptr, nullptr,
        nullptr, out, nullptr, 0, nullptr, nullptr, nullptr);

    (void)in_sizes; (void)n_in; (void)out_size; (void)ws_size;
}

// Round 8
// 328.657 us; speedup vs baseline: 2.5014x; 2.5014x over previous
//
#include <hip/hip_runtime.h>

// Problem constants
#define NN      81920
#define BB      4096
#define PP      20
#define DD      128
#define DOUTT   256
#define MAXDEGG 8
#define NBLK_B  160   // bucketing blocks (160 x 512 = 81920)

using bf16x8 = __attribute__((ext_vector_type(8))) short;
using f32x4  = __attribute__((ext_vector_type(4))) float;
using u16x4  = __attribute__((ext_vector_type(4))) ushort;

__device__ __forceinline__ float b2f(ushort u) {
    union { unsigned u; float f; } v; v.u = ((unsigned)u) << 16; return v.f;
}
__device__ __forceinline__ ushort f2b(float f) {
    union { float f; unsigned u; } v; v.f = f;
    unsigned r = v.u + 0x7fffu + ((v.u >> 16) & 1u);
    return (ushort)(r >> 16);
}
__device__ __forceinline__ float sigm(float x) {
    return __fdividef(1.f, 1.f + __expf(-x));
}
__device__ __forceinline__ float tanh_fast(float x) {
    return 1.f - __fdividef(2.f, 1.f + __expf(2.f * x));
}
__device__ __forceinline__ f32x4 mfma16(bf16x8 a, bf16x8 b, f32x4 c) {
    return __builtin_amdgcn_mfma_f32_16x16x32_bf16(a, b, c, 0, 0, 0);
}
__device__ __forceinline__ bf16x8 pack8(float4 a, float4 b) {
    bf16x8 r;
    r[0] = (short)f2b(a.x); r[1] = (short)f2b(a.y);
    r[2] = (short)f2b(a.z); r[3] = (short)f2b(a.w);
    r[4] = (short)f2b(b.x); r[5] = (short)f2b(b.y);
    r[6] = (short)f2b(b.z); r[7] = (short)f2b(b.w);
    return r;
}
__device__ __forceinline__ bf16x8 ld8_bf(const ushort* p) { return *(const bf16x8*)p; }
__device__ __forceinline__ bf16x8 ld8_f32(const float* p) {
    return pack8(*(const float4*)p, *(const float4*)(p + 4));
}

// ---------------- degree bucketing: atomic-free, stable, deterministic -----
__global__ __launch_bounds__(512) void hist_k(const int* __restrict__ deg,
                                              int* __restrict__ blockHist) {
    __shared__ int wh[8][9];
    const int t = threadIdx.x, w = t >> 6, lane = t & 63;
    int d = deg[blockIdx.x * 512 + t]; d = min(max(d, 0), 8);
#pragma unroll
    for (int c = 0; c < 9; ++c) {
        unsigned long long m = __ballot(d == c);
        if (lane == 0) wh[w][c] = __popcll(m);
    }
    __syncthreads();
    if (t < 9) {
        int s = 0;
#pragma unroll
        for (int w2 = 0; w2 < 8; ++w2) s += wh[w2][t];
        blockHist[blockIdx.x * 9 + t] = s;
    }
}
__global__ void scan_k(const int* __restrict__ blockHist,
                       int* __restrict__ blockBase) {
    __shared__ int classTot[9], classStart[9];
    const int c = threadIdx.x;
    if (c < 9) {
        int s = 0;
        for (int b = 0; b < NBLK_B; ++b) s += blockHist[b * 9 + c];
        classTot[c] = s;
    }
    __syncthreads();
    if (c == 0) {
        int acc = 0;
        for (int k = 0; k < 9; ++k) { classStart[k] = acc; acc += classTot[k]; }
    }
    __syncthreads();
    if (c < 9) {
        int acc = classStart[c];
        for (int b = 0; b < NBLK_B; ++b) {
            blockBase[b * 9 + c] = acc;
            acc += blockHist[b * 9 + c];
        }
    }
}
__global__ __launch_bounds__(512) void scatter_k(const int* __restrict__ deg,
                                                 const int* __restrict__ blockBase,
                                                 int* __restrict__ perm) {
    __shared__ int wh[8][9];
    __shared__ int wbase[8][9];
    const int t = threadIdx.x, w = t >> 6, lane = t & 63;
    const int i = blockIdx.x * 512 + t;
    int d = deg[i]; d = min(max(d, 0), 8);
    int lt = 0;
#pragma unroll
    for (int c = 0; c < 9; ++c) {
        unsigned long long m = __ballot(d == c);
        if (lane == 0) wh[w][c] = __popcll(m);
        if (d == c) lt = __popcll(m & ((1ull << lane) - 1ull));
    }
    __syncthreads();
    if (t < 72) {
        const int w2 = t / 9, c = t - w2 * 9;
        int s = blockBase[blockIdx.x * 9 + c];
        for (int k = 0; k < w2; ++k) s += wh[k][c];
        wbase[w2][c] = s;
    }
    __syncthreads();
    perm[wbase[w][d] + lt] = i;
}

// ---------------- BN stats over feat (f32) ----------------
__global__ __launch_bounds__(256) void bn_stats(const float* __restrict__ X,
                                                float* __restrict__ part) {
    const int tid  = threadIdx.x;
    const int col  = tid & 127;
    const int half = tid >> 7;
    const long base = (long)blockIdx.x * 128 + (long)half * 64;
    float s = 0.f, q = 0.f;
    for (int i = 0; i < 64; ++i) {
        float x = X[(base + i) * 128 + col];
        s += x; q += x * x;
    }
    __shared__ float red[2][2][128];
    red[0][half][col] = s;
    red[1][half][col] = q;
    __syncthreads();
    if (tid < 128) {
        part[blockIdx.x * 128 + tid]             = red[0][0][tid] + red[0][1][tid];
        part[640 * 128 + blockIdx.x * 128 + tid] = red[1][0][tid] + red[1][1][tid];
    }
}

// 128 blocks (one per column) x 256 threads; parallel latency-hiding reduce.
// (R7 lesson: the 1-block runtime-bound loop serialized into a ~900cy/iter
//  cross-XCD HBM latency chain -> 340us. 32K threads hide it completely.)
__global__ __launch_bounds__(256) void bn_final(const float* __restrict__ part, int nparts,
                                                const float* __restrict__ g,
                                                const float* __restrict__ b,
                                                float2* __restrict__ ss) {
    const int c = blockIdx.x;
    const int t = threadIdx.x;
    float s = 0.f, q = 0.f;
    for (int i = t; i < nparts; i += 256) {
        s += part[(long)i * 128 + c];
        q += part[(long)(nparts + i) * 128 + c];
    }
#pragma unroll
    for (int off = 32; off > 0; off >>= 1) {
        s += __shfl_xor(s, off, 64);
        q += __shfl_xor(q, off, 64);
    }
    __shared__ float rs[4], rq[4];
    if ((t & 63) == 0) { rs[t >> 6] = s; rq[t >> 6] = q; }
    __syncthreads();
    if (t == 0) {
        s = rs[0] + rs[1] + rs[2] + rs[3];
        q = rq[0] + rq[1] + rq[2] + rq[3];
        const float inv_n = 1.f / (float)NN;
        float mean = s * inv_n;
        float var  = q * inv_n - mean * mean;
        float rstd = rsqrtf(var + 1e-5f);
        float sc = g[c] * rstd;
        ss[c] = make_float2(sc, b[c] - mean * sc);
    }
}

// ---------------- Generic fused GEMM --------------------------------------
// out[m,c] = sum_k A1[m,k]W1'[c,k] + (KPARTS==2) A2[m2,k]W2'[c,k] + biases
// FOLDx: W' = sc*W folded at load; fold-bias = sum_k sh[k]W[c,k] via shfl.
// OUTMODE: 0=bf16 out, 1=f32 out, 2=bf16 out + BN-stats partials,
//          3=e-epilogue only (e[row] = sum_c sigm(v+fvl[b,c])*We[c])
template <int NCOL, int KPARTS, bool A1F32, bool GATHER2, bool BIAS1, bool BIAS2,
          bool FOLD1, bool FOLD2, int OUTMODE>
__global__ __launch_bounds__(256) void gemm_bt(
    const void* __restrict__ A1, const void* __restrict__ A2,
    const float* __restrict__ W1, const float* __restrict__ W2,
    const float* __restrict__ bias1, const float* __restrict__ bias2,
    const float2* __restrict__ ssW1, const float2* __restrict__ ssW2,
    const int* __restrict__ gidx, void* __restrict__ outv,
    float* __restrict__ part, int nparts,
    const float* __restrict__ fvl, const float* __restrict__ We,
    float* __restrict__ e) {
    constexpr int JT = NCOL / 64;
    __shared__ float epart[4][64];
    const int tid = threadIdx.x;
    const int w   = tid >> 6;
    const int l   = tid & 63;
    const int l15 = l & 15;
    const int l4  = l >> 4;
    const int colbase = w * (NCOL / 4);

    bf16x8 bfr[JT][KPARTS * 4];
    float bv[JT];
    float Wec[JT];
#pragma unroll
    for (int jl = 0; jl < JT; ++jl) {
        const int wrow = colbase + jl * 16 + l15;
        float fb = 0.f;
#pragma unroll
        for (int kp = 0; kp < KPARTS; ++kp) {
            const float* Wp = (kp == 0) ? W1 : W2;
            const float2* sp = (kp == 0) ? ssW1 : ssW2;
            const bool fold = (kp == 0) ? FOLD1 : FOLD2;
#pragma unroll
            for (int kt = 0; kt < 4; ++kt) {
                const float* wp = &Wp[(long)wrow * 128 + kt * 32 + l4 * 8];
                float4 a = *(const float4*)wp;
                float4 b4 = *(const float4*)(wp + 4);
                if (fold) {
                    const float* s = (const float*)(sp + kt * 32 + l4 * 8);
                    float4 s0 = *(const float4*)s, s1 = *(const float4*)(s + 4);
                    float4 s2 = *(const float4*)(s + 8), s3 = *(const float4*)(s + 12);
                    fb += s0.y * a.x + s0.w * a.y + s1.y * a.z + s1.w * a.w
                        + s2.y * b4.x + s2.w * b4.y + s3.y * b4.z + s3.w * b4.w;
                    a.x *= s0.x; a.y *= s0.z; a.z *= s1.x; a.w *= s1.z;
                    b4.x *= s2.x; b4.y *= s2.z; b4.z *= s3.x; b4.w *= s3.z;
                }
                bfr[jl][kp * 4 + kt] = pack8(a, b4);
            }
        }
        if (FOLD1 || FOLD2) {
            fb += __shfl_xor(fb, 16, 64);
            fb += __shfl_xor(fb, 32, 64);
        }
        if (BIAS1) fb += bias1[wrow];
        if (BIAS2) fb += bias2[wrow];
        bv[jl] = fb;
        if (OUTMODE == 3) Wec[jl] = We[wrow];
    }

    const int rowblk = blockIdx.x * 64;
    const f32x4 fz = {0.f, 0.f, 0.f, 0.f};
    float ssum[JT], sq[JT];
#pragma unroll
    for (int jl = 0; jl < JT; ++jl) { ssum[jl] = 0.f; sq[jl] = 0.f; }

#pragma unroll
    for (int it = 0; it < 4; ++it) {
        const int arow1 = rowblk + it * 16 + l15;
        bf16x8 afr[KPARTS * 4];
#pragma unroll
        for (int kt = 0; kt < 4; ++kt) {
            if (A1F32)
                afr[kt] = ld8_f32(&((const float*)A1)[(long)arow1 * 128 + kt * 32 + l4 * 8]);
            else
                afr[kt] = ld8_bf(&((const ushort*)A1)[(long)arow1 * 128 + kt * 32 + l4 * 8]);
        }
        if (KPARTS == 2) {
            const long arow2 = GATHER2 ? (long)gidx[arow1] : (long)arow1;
#pragma unroll
            for (int kt = 0; kt < 4; ++kt)
                afr[4 + kt] = ld8_bf(&((const ushort*)A2)[arow2 * 128 + kt * 32 + l4 * 8]);
        }
        f32x4 acc[JT];
#pragma unroll
        for (int jl = 0; jl < JT; ++jl) {
            acc[jl] = fz;
#pragma unroll
            for (int kk = 0; kk < KPARTS * 4; ++kk)
                acc[jl] = mfma16(afr[kk], bfr[jl][kk], acc[jl]);
        }
        float ps[4] = {0.f, 0.f, 0.f, 0.f};
#pragma unroll
        for (int jl = 0; jl < JT; ++jl) {
            const int col = colbase + jl * 16 + l15;
#pragma unroll
            for (int r = 0; r < 4; ++r) {
                const long orow = rowblk + it * 16 + l4 * 4 + r;
                float v = acc[jl][r] + bv[jl];
                if (OUTMODE == 0 || OUTMODE == 2)
                    ((ushort*)outv)[orow * NCOL + col] = f2b(v);
                if (OUTMODE == 1)
                    ((float*)outv)[orow * NCOL + col] = v;
                if (OUTMODE == 2) { ssum[jl] += v; sq[jl] += v * v; }
                if (OUTMODE == 3) {
                    const int b = (int)orow / PP;
                    ps[r] += sigm(v + fvl[(long)b * 128 + col]) * Wec[jl];
                }
            }
        }
        if (OUTMODE == 3) {
#pragma unroll
            for (int r = 0; r < 4; ++r) {
#pragma unroll
                for (int off = 1; off < 16; off <<= 1)
                    ps[r] += __shfl_xor(ps[r], off, 64);
            }
            if (l15 == 0) {
#pragma unroll
                for (int r = 0; r < 4; ++r)
                    epart[w][it * 16 + l4 * 4 + r] = ps[r];
            }
        }
    }
    if (OUTMODE == 2) {
#pragma unroll
        for (int jl = 0; jl < JT; ++jl) {
            float s = ssum[jl], q = sq[jl];
            s += __shfl_xor(s, 16, 64); s += __shfl_xor(s, 32, 64);
            q += __shfl_xor(q, 16, 64); q += __shfl_xor(q, 32, 64);
            if (l4 == 0) {
                const int col = colbase + jl * 16 + l15;
                part[(long)blockIdx.x * 128 + col] = s;
                part[(long)nparts * 128 + (long)blockIdx.x * 128 + col] = q;
            }
        }
    }
    if (OUTMODE == 3) {
        __syncthreads();
        if (tid < 64)
            e[rowblk + tid] = epart[0][tid] + epart[1][tid] + epart[2][tid] + epart[3][tid];
    }
}

// ---------------- Fused ragged GRU, degree-sorted blocks -------------------
// 8 waves x 64 same-degree nodes; wave owns 16 cols. Cross-barrier prefetch
// of its{0,1} gathers (12 VGPRs); waves_per_eu(4,4) pins occupancy so the
// allocator can use up to 128 VGPRs without spilling (R6 lesson).
__global__ __attribute__((amdgpu_flat_work_group_size(512, 512), amdgpu_waves_per_eu(4, 4)))
void gru_kernel(const ushort* __restrict__ G,
                const float* __restrict__ Whh,
                const float* __restrict__ bhh,
                const int* __restrict__ nbr_idx,
                const int* __restrict__ deg,
                const int* __restrict__ perm,
                ushort* __restrict__ neigh) {
    __shared__ alignas(16) ushort hbuf[2][64][136];
    __shared__ alignas(16) int nbrs[64][8];
    __shared__ int degs[64];
    __shared__ int nid[64];

    const int tid = threadIdx.x;
    const int w   = tid >> 6;
    const int l   = tid & 63;
    const int l15 = l & 15;
    const int l4  = l >> 4;
    const int blockRow = (gridDim.x - 1 - blockIdx.x) * 64;  // high-deg first
    const int colbase = w * 16;
    const int c0 = colbase + l4 * 4;

    if (tid < 64) nid[tid] = perm[blockRow + tid];
    {
        bf16x8 z = {0, 0, 0, 0, 0, 0, 0, 0};
        bf16x8* p = (bf16x8*)&hbuf[0][0][0];
        for (int i = tid; i < 64 * 136 / 8; i += 512) p[i] = z;
    }
    __syncthreads();
    nbrs[tid >> 3][tid & 7] = nbr_idx[(long)nid[tid >> 3] * 8 + (tid & 7)];
    if (tid < 64) degs[tid] = deg[nid[tid]];

    bf16x8 bfr[3][4];
#pragma unroll
    for (int g = 0; g < 3; ++g)
#pragma unroll
        for (int kt = 0; kt < 4; ++kt)
            bfr[g][kt] = ld8_f32(&Whh[(long)(g * 128 + colbase + l15) * 128 + kt * 32 + l4 * 8]);
    f32x4 binit[3];
#pragma unroll
    for (int g = 0; g < 3; ++g)
        binit[g] = *(const f32x4*)&bhh[g * 128 + c0];
    __syncthreads();

    int dreg[4];
#pragma unroll
    for (int it = 0; it < 4; ++it) dreg[it] = degs[it * 16 + l15];
    int dmax = degs[l];
#pragma unroll
    for (int off = 32; off > 0; off >>= 1) dmax = max(dmax, __shfl_xor(dmax, off, 64));
    dmax = __builtin_amdgcn_readfirstlane(dmax);

    // cross-barrier prefetch buffer for its {0,1}
    u16x4 gP[2][3];
#pragma unroll
    for (int it = 0; it < 2; ++it) {
        gP[it][0] = (u16x4){0,0,0,0}; gP[it][1] = (u16x4){0,0,0,0}; gP[it][2] = (u16x4){0,0,0,0};
        if (0 < dreg[it]) {
            const ushort* Grow = G + (long)nbrs[it * 16 + l15][0] * 384;
            gP[it][0] = *(const u16x4*)&Grow[c0];
            gP[it][1] = *(const u16x4*)&Grow[c0 + 128];
            gP[it][2] = *(const u16x4*)&Grow[c0 + 256];
        }
    }

    int cur = 0;
    for (int t = 0; t < dmax; ++t) {
        // in-step loads for its {2,3} (compiler hoists these early)
        u16x4 g23[2][3];
#pragma unroll
        for (int it = 2; it < 4; ++it) {
            u16x4* gd = g23[it - 2];
            gd[0] = (u16x4){0,0,0,0}; gd[1] = (u16x4){0,0,0,0}; gd[2] = (u16x4){0,0,0,0};
            if (t < dreg[it]) {
                const ushort* Grow = G + (long)nbrs[it * 16 + l15][t] * 384;
                gd[0] = *(const u16x4*)&Grow[c0];
                gd[1] = *(const u16x4*)&Grow[c0 + 128];
                gd[2] = *(const u16x4*)&Grow[c0 + 256];
            }
        }

#pragma unroll
        for (int it = 0; it < 2; ++it) {
            const int row = it * 16 + l15;
            const bool upd = (t < dreg[it]);
            bf16x8 af[4];
#pragma unroll
            for (int kt = 0; kt < 4; ++kt)
                af[kt] = *(const bf16x8*)&hbuf[cur][row][kt * 32 + l4 * 8];
            f32x4 ar = binit[0], az = binit[1], an = binit[2];
#pragma unroll
            for (int kt = 0; kt < 4; ++kt) {
                ar = mfma16(bfr[0][kt], af[kt], ar);
                az = mfma16(bfr[1][kt], af[kt], az);
                an = mfma16(bfr[2][kt], af[kt], an);
            }
            const u16x4 hold = *(const u16x4*)&hbuf[cur][row][c0];
            u16x4 hnew = hold;
            if (upd) {
#pragma unroll
                for (int r = 0; r < 4; ++r) {
                    const float rr = sigm(b2f(gP[it][0][r]) + ar[r]);
                    const float zz = sigm(b2f(gP[it][1][r]) + az[r]);
                    const float nn = tanh_fast(b2f(gP[it][2][r]) + rr * an[r]);
                    hnew[r] = f2b((1.f - zz) * nn + zz * b2f(hold[r]));
                }
            }
            *(u16x4*)&hbuf[1 - cur][row][c0] = hnew;
        }

        // prefetch NEXT step's its {0,1}; latency hides under its {2,3} compute
#pragma unroll
        for (int it = 0; it < 2; ++it) {
            gP[it][0] = (u16x4){0,0,0,0}; gP[it][1] = (u16x4){0,0,0,0}; gP[it][2] = (u16x4){0,0,0,0};
            if (t + 1 < dreg[it]) {
                const ushort* Grow = G + (long)nbrs[it * 16 + l15][t + 1] * 384;
                gP[it][0] = *(const u16x4*)&Grow[c0];
                gP[it][1] = *(const u16x4*)&Grow[c0 + 128];
                gP[it][2] = *(const u16x4*)&Grow[c0 + 256];
            }
        }

#pragma unroll
        for (int it = 2; it < 4; ++it) {
            const int row = it * 16 + l15;
            const bool upd = (t < dreg[it]);
            bf16x8 af[4];
#pragma unroll
            for (int kt = 0; kt < 4; ++kt)
                af[kt] = *(const bf16x8*)&hbuf[cur][row][kt * 32 + l4 * 8];
            f32x4 ar = binit[0], az = binit[1], an = binit[2];
#pragma unroll
            for (int kt = 0; kt < 4; ++kt) {
                ar = mfma16(bfr[0][kt], af[kt], ar);
                az = mfma16(bfr[1][kt], af[kt], az);
                an = mfma16(bfr[2][kt], af[kt], an);
            }
            const u16x4 hold = *(const u16x4*)&hbuf[cur][row][c0];
            u16x4 hnew = hold;
            if (upd) {
#pragma unroll
                for (int r = 0; r < 4; ++r) {
                    const float rr = sigm(b2f(g23[it - 2][0][r]) + ar[r]);
                    const float zz = sigm(b2f(g23[it - 2][1][r]) + az[r]);
                    const float nn = tanh_fast(b2f(g23[it - 2][2][r]) + rr * an[r]);
                    hnew[r] = f2b((1.f - zz) * nn + zz * b2f(hold[r]));
                }
            }
            *(u16x4*)&hbuf[1 - cur][row][c0] = hnew;
        }
        __syncthreads();
        cur ^= 1;
    }
    for (int idx = tid; idx < 64 * 16; idx += 512) {
        const int row = idx >> 4, ch = idx & 15;
        bf16x8* dst = (bf16x8*)(neigh + (long)nid[row] * 128);
        dst[ch] = *(const bf16x8*)&hbuf[cur][row][ch * 8];
    }
}

// ---------------- fused softmax + segment sums (BN2 applied on the fly) ----
__global__ __launch_bounds__(256) void seg_k(const ushort* __restrict__ rst,
                                             const float* __restrict__ e,
                                             const float* __restrict__ pw,
                                             const float2* __restrict__ ss2,
                                             ushort* __restrict__ s12) {
    const int g = blockIdx.x * 2 + (threadIdx.x >> 7);
    const int c = threadIdx.x & 127;
    const float2 sc = ss2[c];
    float ev[PP];
    float m = -1e30f;
#pragma unroll
    for (int p = 0; p < PP; ++p) { ev[p] = e[g * PP + p]; m = fmaxf(m, ev[p]); }
    float sum = 0.f;
#pragma unroll
    for (int p = 0; p < PP; ++p) { ev[p] = __expf(ev[p] - m); sum += ev[p]; }
    const float inv = __fdividef(1.f, sum);
    float a1 = 0.f, a2 = 0.f;
#pragma unroll
    for (int p = 0; p < PP; ++p) {
        const int node = g * PP + p;
        const float hv = b2f(rst[(long)node * 128 + c]) * sc.x + sc.y;
        a1 += (ev[p] * inv) * hv;
        a2 += pw[node] * hv;
    }
    s12[(long)g * 128 + c]        = f2b(a1);
    s12[(long)(BB + g) * 128 + c] = f2b(a2);
}

// ---------------------------------------------------------------------------
extern "C" void kernel_launch(void* const* d_in, const int* in_sizes, int n_in,
                              void* d_out, int out_size, void* d_ws, size_t ws_size,
                              hipStream_t stream) {
    const float* feat    = (const float*)d_in[0];
    const float* intend  = (const float*)d_in[1];
    const float* pw      = (const float*)d_in[2];
    const int*   nbr_idx = (const int*)d_in[3];
    const int*   deg     = (const int*)d_in[4];
    const int*   last    = (const int*)d_in[5];
    const float* bn1_g   = (const float*)d_in[6];
    const float* bn1_b   = (const float*)d_in[7];
    const float* W_ih    = (const float*)d_in[8];
    const float* W_hh    = (const float*)d_in[9];
    const float* b_ih    = (const float*)d_in[10];
    const float* b_hh    = (const float*)d_in[11];
    const float* W_self  = (const float*)d_in[12];
    const float* W_neigh = (const float*)d_in[13];
    const float* bn2_g   = (const float*)d_in[14];
    const float* bn2_b   = (const float*)d_in[15];
    const float* Wu      = (const float*)d_in[16];
    const float* Wv      = (const float*)d_in[17];
    const float* bv      = (const float*)d_in[18];
    const float* Wi      = (const float*)d_in[19];
    const float* bi      = (const float*)d_in[20];
    const float* We      = (const float*)d_in[21];
    const float* Wout    = (const float*)d_in[22];
    float* out = (float*)d_out;
    char* ws = (char*)d_ws;

    // workspace layout (bytes)
    ushort* G     = (ushort*)(ws + 0L);              // 62,914,560  [N,384] bf16
    ushort* rst   = G;                               // alias (G dead after gru)
    ushort* neigh = (ushort*)(ws + 62914560L);       // 20,971,520
    float*  fvl   = (float*)(ws + 83886080L);        // 2,097,152
    float*  e     = (float*)(ws + 85983232L);        // 327,680
    ushort* s12   = (ushort*)(ws + 86310912L);       // 2,097,152
    float*  part1 = (float*)(ws + 88408064L);        // 655,360
    float*  part2 = (float*)(ws + 89063424L);        // 1,310,720
    int*    perm  = (int*)(ws + 90374144L);          // 327,680
    float2* ss1   = (float2*)(ws + 90701824L);       // 1,024
    float2* ss2   = (float2*)(ws + 90702848L);       // 1,024
    int*    blockHist = (int*)(ws + 90703872L);      // 5,760
    int*    blockBase = (int*)(ws + 90709632L);      // 5,760

    // ---- BN1 stats only (apply is folded into W of downstream GEMMs) ----
    bn_stats<<<640, 256, 0, stream>>>(feat, part1);
    bn_final<<<128, 256, 0, stream>>>(part1, 640, bn1_g, bn1_b, ss1);

    // ---- degree bucketing (atomic-free) -> perm ----
    hist_k<<<NBLK_B, 512, 0, stream>>>(deg, blockHist);
    scan_k<<<1, 16, 0, stream>>>(blockHist, blockBase);
    scatter_k<<<NBLK_B, 512, 0, stream>>>(deg, blockBase, perm);

    // ---- G = bn1(feat) @ W_ih.T + b_ih   (BN folded into W_ih) ----
    gemm_bt<384, 1, true, false, true, false, true, false, 0><<<1280, 256, 0, stream>>>(
        feat, nullptr, W_ih, nullptr, b_ih, nullptr, ss1, nullptr,
        nullptr, G, nullptr, 0, nullptr, nullptr, nullptr);

    // ---- ragged GRU (degree-sorted, high-deg first) -> neigh ----
    gru_kernel<<<1280, 512, 0, stream>>>(G, W_hh, b_hh, nbr_idx, deg, perm, neigh);

    // ---- rst = bn1(feat)@W_self.T + neigh@W_neigh.T  (+BN2-stats epilogue) ----
    gemm_bt<128, 2, true, false, false, false, true, false, 2><<<1280, 256, 0, stream>>>(
        feat, neigh, W_self, W_neigh, nullptr, nullptr, ss1, nullptr,
        nullptr, rst, part2, 1280, nullptr, nullptr, nullptr);
    bn_final<<<128, 256, 0, stream>>>(part2, 1280, bn2_g, bn2_b, ss2);

    // ---- fvl = intend@Wv.T + bv + bn2(rst)[last]@Wi.T + bi  (f32) ----
    gemm_bt<128, 2, true, true, true, true, false, true, 1><<<64, 256, 0, stream>>>(
        intend, rst, Wv, Wi, bv, bi, nullptr, ss2,
        last, fvl, nullptr, 0, nullptr, nullptr, nullptr);

    // ---- e[row] = sum_c sigm(bn2(rst)@Wu.T + fvl) * We  (fu never stored) ----
    gemm_bt<128, 1, false, false, false, false, true, false, 3><<<1280, 256, 0, stream>>>(
        rst, nullptr, Wu, nullptr, nullptr, nullptr, ss2, nullptr,
        nullptr, nullptr, nullptr, 0, fvl, We, e);

    // ---- fused softmax + segment sums -> s12 ----
    seg_k<<<2048, 256, 0, stream>>>(rst, e, pw, ss2, s12);

    // ---- [rst_g; pos] = s12 @ Wout.T -> d_out (f32) ----
    gemm_bt<256, 1, false, false, false, false, false, false, 1><<<128, 256, 0, stream>>>(
        s12, nullptr, Wout, nullptr, nullptr, nullptr, nullptr, nullptr,
        nullptr, out, nullptr, 0, nullptr, nullptr, nullptr);

    (void)in_sizes; (void)n_in; (void)out_size; (void)ws_size;
}